// Round 12
// baseline (142.385 us; speedup 1.0000x reference)
//
#include <hip/hip_runtime.h>
#include <hip/hip_bf16.h>

// Motion-detection Gauss-LIF SNN:
//   K01 (fused, heterogeneous 256-thread blocks) — r10-proven form:
//     blocks [0,512):    conv(16x9x9) via MFMA bf16 16x16x32 + LIF1 ->
//                        Z1 [800][65536] i8 {0,1} in k'-order (SW=84,
//                        narrow wave-parity reads, separate limb arrays).
//     blocks [512,6912): w1 -> i8 (A,B) split, k'-permuted, conflict-free LDS.
//   K2: Z1 @ w1^T via two mfma_i32_16x16x64_i8 (exact i32). BM=128, KSPL=32,
//       XCD-chunked. NEW: A-fragments direct from global (no LDS round trip),
//       double-buffered B tile, 1 barrier per k-step.
//   K2b: reduce partials; K3: sequential LIF2+FC2+LIF3 scan.
// LIF recurrences __fmul_rn/__fadd_rn (no contract). Deterministic order.

typedef __attribute__((ext_vector_type(8))) short short8;
typedef __attribute__((ext_vector_type(4))) float f32x4;
typedef __attribute__((ext_vector_type(4))) int   i32x4;

#define B_   16
#define T_   50
#define HW_  4096
#define K1N  65536
#define M_   800
#define N2_  200
#define NP_  256
#define KSPL 32
#define BM2  128
#define BK2  64
#define KCH  (K1N / KSPL)  // 2048
#define MT2  7             // ceil(800/128)
#define SW   84            // conv tile stride (ushorts), r7/r10-proven
#define TILE (12 * SW)     // 1008
#define NCONV 512
#define NPERM (200 * 32)

static __device__ __forceinline__ short8 mk8(uint a, uint b, uint c, uint d){
  union { uint u[4]; short8 v; } x;
  x.u[0] = a; x.u[1] = b; x.u[2] = c; x.u[3] = d;
  return x.v;
}
static __device__ __forceinline__ uint fnl(uint a, uint b){ return (a >> 16) | (b << 16); }

// ---------------------------------------------------------------- conv helpers (r7/r10)
template<bool WODD>
static __device__ __forceinline__ void rd5(const uint* p, int dw, uint e[5]){
  if (WODD){
    e[0] = p[dw];
    uint2 a = *(const uint2*)(p + dw + 1);
    uint2 b = *(const uint2*)(p + dw + 3);
    e[1] = a.x; e[2] = a.y; e[3] = b.x; e[4] = b.y;
  } else {
    uint2 a = *(const uint2*)(p + dw);
    uint2 b = *(const uint2*)(p + dw + 2);
    e[0] = a.x; e[1] = a.y; e[2] = b.x; e[3] = b.y;
    e[4] = p[dw + 4];
  }
}

template<bool WODD>
static __device__ __forceinline__ void conv_phase(const uint* T0, const uint* T1,
                                                  int bdw,
                                                  const short8 (&afh)[5],
                                                  const short8 (&afl)[5],
                                                  f32x4& acc0, f32x4& acc1){
  #pragma unroll
  for (int ks = 0; ks < 5; ++ks){
    const int dw = bdw + (SW / 2) * 2 * ks;   // +84 dwords per kstep (2 rows)
    uint h[5], m[5];
    rd5<WODD>(T0, dw, h);
    rd5<WODD>(T1, dw, m);
    short8 bh0 = mk8(h[0], h[1], h[2], h[3]);
    short8 bm0 = mk8(m[0], m[1], m[2], m[3]);
    acc0 = __builtin_amdgcn_mfma_f32_16x16x32_bf16(afh[ks], bh0, acc0, 0, 0, 0);
    acc0 = __builtin_amdgcn_mfma_f32_16x16x32_bf16(afh[ks], bm0, acc0, 0, 0, 0);
    acc0 = __builtin_amdgcn_mfma_f32_16x16x32_bf16(afl[ks], bh0, acc0, 0, 0, 0);
    short8 bh1 = mk8(fnl(h[0], h[1]), fnl(h[1], h[2]), fnl(h[2], h[3]), fnl(h[3], h[4]));
    short8 bm1 = mk8(fnl(m[0], m[1]), fnl(m[1], m[2]), fnl(m[2], m[3]), fnl(m[3], m[4]));
    acc1 = __builtin_amdgcn_mfma_f32_16x16x32_bf16(afh[ks], bh1, acc1, 0, 0, 0);
    acc1 = __builtin_amdgcn_mfma_f32_16x16x32_bf16(afh[ks], bm1, acc1, 0, 0, 0);
    acc1 = __builtin_amdgcn_mfma_f32_16x16x32_bf16(afl[ks], bh1, acc1, 0, 0, 0);
  }
}

static __device__ __forceinline__ void stage_tile(ushort* Th, ushort* Tm,
                                                  int eb, float4 f){
  float vv[4] = {f.x, f.y, f.z, f.w};
  ushort sh[4], sm[4];
  #pragma unroll
  for (int ii = 0; ii < 4; ++ii){
    __hip_bfloat16 h = __float2bfloat16(vv[ii]);
    float t1 = vv[ii] - __bfloat162float(h);
    __hip_bfloat16 m = __float2bfloat16(t1);
    sh[ii] = *reinterpret_cast<ushort*>(&h);
    sm[ii] = *reinterpret_cast<ushort*>(&m);
  }
  *(ushort4*)(Th + eb) = make_ushort4(sh[0], sh[1], sh[2], sh[3]);
  *(ushort4*)(Tm + eb) = make_ushort4(sm[0], sm[1], sm[2], sm[3]);
}

// ---------------------------------------------------------------- K01 (r10 verbatim)
__global__ __launch_bounds__(256) void k01_fused(const float* __restrict__ x,
                                                 const float* __restrict__ kern,
                                                 const float* __restrict__ w1,
                                                 unsigned char* __restrict__ zout,
                                                 char* __restrict__ wa,
                                                 char* __restrict__ wb){
  __shared__ __align__(16) ushort smem[9152];
  const int bid = blockIdx.x;
  const int tid = threadIdx.x;

  if (bid >= NCONV){
    // ---------------- w1 -> i8 (A,B) split + k'-permute, conflict-free ------
    uint* la = (uint*)smem;               // 520 uints (o-padded)
    uint* lb = ((uint*)smem) + 528;
    const int bid2 = bid - NCONV;
    const int n = bid2 >> 5;
    const int strip = bid2 & 31;
    const int p128 = tid & 127;
    const int qp   = tid >> 7;            // 0 or 1
    const int o = p128 & 7, s = p128 >> 3;
    const float* src = w1 + (size_t)n * K1N + strip * 128 + p128;
    #pragma unroll
    for (int qi = 0; qi < 2; ++qi){
      const int q = 2 * qp + qi;
      uint ua = 0, ub = 0;
      #pragma unroll
      for (int r = 0; r < 4; ++r){
        float v = src[(size_t)(4 * q + r) * 4096];
        float af = rintf(v * 16384.f);     // |af| <= 64
        float rr = v - af * 0x1p-14f;      // exact (Sterbenz)
        float bf = rintf(rr * 0x1p22f);    // in [-128, 128]
        int A = (int)af, Bq = (int)bf;
        if (Bq == 128){ A += 1; Bq = -128; }
        ua |= ((uint)(A & 255))  << (8 * r);
        ub |= ((uint)(Bq & 255)) << (8 * r);
      }
      const int u = 64 * o + 4 * s + q + o;   // +o pad -> <=2-way (free)
      la[u] = ua;
      lb[u] = ub;
    }
    __syncthreads();
    {
      const int j0 = 2 * tid;               // 0..510
      const int o2 = j0 >> 6;
      uint a0 = la[j0 + o2], a1 = la[j0 + 1 + o2];
      uint b0 = lb[j0 + o2], b1 = lb[j0 + 1 + o2];
      const size_t ob = (size_t)n * K1N + strip * 2048 + (size_t)j0 * 4;
      *(uint2*)(wa + ob) = make_uint2(a0, a1);
      *(uint2*)(wb + ob) = make_uint2(b0, b1);
    }
    return;
  }

  // ---------------- conv + LIF1 path (r10 verbatim) ----------------
  ushort* Ah  = smem;
  ushort* Alo = smem + 2560;
  ushort* Tt  = smem + 5120;               // [buf][limb][TILE]

  const int strip = bid & 31;
  const int b = bid >> 5;
  const int w = tid >> 6;
  const int l = tid & 63;
  const int q = l >> 4;
  const int s = l & 15;

  for (int slot = tid; slot < 16 * 160; slot += 256){
    int ch = slot / 160, kk = slot - ch * 160;
    int dy = kk >> 4, dx = kk & 15;
    float v = 0.f;
    if (dy < 9 && dx < 9) v = kern[ch * 81 + dy * 9 + dx];
    __hip_bfloat16 h = __float2bfloat16(v);
    float hf = __bfloat162float(h);
    __hip_bfloat16 lo = __float2bfloat16(v - hf);
    Ah[slot]  = *reinterpret_cast<ushort*>(&h);
    Alo[slot] = *reinterpret_cast<ushort*>(&lo);
  }

  const bool sact = tid < 240;
  const int sr = tid / 20, sc4 = tid - sr * 20;
  const int r0 = 2 * strip - 4;
  const int imr = r0 + sr;
  const bool sin = sact && imr >= 0 && imr < 64 && sc4 >= 1 && sc4 <= 16;
  const float* xb = x + (size_t)b * (T_ * HW_);
  const float* xsrc = xb + (sin ? (imr * 64 + (sc4 - 1) * 4) : 0);
  const int eb = sr * SW + sc4 * 4;

  {
    float4 f0 = make_float4(0.f, 0.f, 0.f, 0.f);
    if (sin) f0 = *(const float4*)(xsrc);
    if (sact) stage_tile(Tt + 0 * TILE, Tt + 1 * TILE, eb, f0);
  }
  __syncthreads();

  short8 afh[5], afl[5];
  #pragma unroll
  for (int ks = 0; ks < 5; ++ks){
    afh[ks] = *(const short8*)(Ah + s * 160 + ks * 32 + q * 8);
    afl[ks] = *(const short8*)(Alo + s * 160 + ks * 32 + q * 8);
  }

  const int p0 = (s >> 3) + (q >> 1);
  const int bdw = 42 * p0 + 4 * (s & 7) + 4 * (q & 1) + w;
  const bool wodd = (w & 1) != 0;

  float m1v[2][4];
  #pragma unroll
  for (int oi = 0; oi < 2; ++oi)
    #pragma unroll
    for (int r = 0; r < 4; ++r) m1v[oi][r] = 0.f;

  for (int t = 0; t < T_; ++t){
    __syncthreads();                           // tile t&1 ready
    float4 nfx = make_float4(0.f, 0.f, 0.f, 0.f);
    if (t + 1 < T_ && sin) nfx = *(const float4*)(xsrc + (size_t)(t + 1) * HW_);

    const int bb = t & 1;
    const uint* T0 = (const uint*)(Tt + (bb * 2 + 0) * TILE);
    const uint* T1 = (const uint*)(Tt + (bb * 2 + 1) * TILE);
    f32x4 acc0 = (f32x4)(0.f), acc1 = (f32x4)(0.f);
    if (wodd) conv_phase<true >(T0, T1, bdw, afh, afl, acc0, acc1);
    else      conv_phase<false>(T0, T1, bdw, afh, afl, acc0, acc1);

    const size_t zr = ((size_t)(t * B_ + b)) * K1N + strip * 2048 + s * 16 + q * 4;
    {
      uint zw = 0;
      #pragma unroll
      for (int r = 0; r < 4; ++r){
        float m = m1v[0][r];
        float nm = (m > 1.0f) ? 0.0f : __fadd_rn(__fmul_rn(0.9f, m), acc0[r]);
        m1v[0][r] = nm;
        if (nm > 1.0f) zw |= (1u << (8 * r));
      }
      *(uint*)(zout + zr + (size_t)(2 * w) * 256) = zw;
    }
    {
      uint zw = 0;
      #pragma unroll
      for (int r = 0; r < 4; ++r){
        float m = m1v[1][r];
        float nm = (m > 1.0f) ? 0.0f : __fadd_rn(__fmul_rn(0.9f, m), acc1[r]);
        m1v[1][r] = nm;
        if (nm > 1.0f) zw |= (1u << (8 * r));
      }
      *(uint*)(zout + zr + (size_t)(2 * w + 1) * 256) = zw;
    }

    if (t + 1 < T_ && sact)
      stage_tile(Tt + ((bb ^ 1) * 2 + 0) * TILE, Tt + ((bb ^ 1) * 2 + 1) * TILE, eb, nfx);
  }
}

// ---------------------------------------------------------------- K2 B-loader (i8)
static __device__ __forceinline__ void k2_loadB(const char* __restrict__ wa,
                                                const char* __restrict__ wb,
                                                int kg, int tid, uint4 pb[4]){
  #pragma unroll
  for (int i = 0; i < 4; ++i){
    int idx = tid + 512 * i;               // 0..2047
    int g   = idx >> 2;                    // row 0..511
    int c16 = idx & 3;
    int sel = g >> 8;
    int r   = g & 255;
    const char* src = sel ? wb : wa;
    pb[i] = make_uint4(0, 0, 0, 0);
    if (r < N2_) pb[i] = *(const uint4*)(src + (size_t)r * K1N + kg + c16 * 16);
  }
}

// ---------------------------------------------------------------- K2: i8 MFMA GEMM
// grid 224 = m-tile(7 x 128) x k-split(32 x 2048); block 512 = 8 waves
// (2 m-halves x 4 n-quads). A-fragments load DIRECT from global (L1-shared,
// 64B-granule coalesced); B double-buffered in LDS, 1 barrier per k-step.
__global__ __launch_bounds__(512) void k2_gemm(const unsigned char* __restrict__ z,
                                               const char* __restrict__ wa,
                                               const char* __restrict__ wb,
                                               float* __restrict__ P){
  __shared__ __align__(16) unsigned char Bw[2][512 * 80];

  const int bid = blockIdx.x;
  const int L = (bid & 7) * 28 + (bid >> 3);      // bijective: 224 = 8*28
  const int ks = L / MT2;
  const int mt = L % MT2;
  const int m0 = mt * BM2;
  const int k0 = ks * KCH;
  const int tid = threadIdx.x;
  const int wv = tid >> 6;
  const int mh = wv >> 2;
  const int nq = wv & 3;
  const int l  = tid & 63;
  const int lr = l & 15;
  const int lq = l >> 4;

  // per-lane A row pointers (clamped: epilogue guards m < M_; clamp keeps
  // reads inside the z allocation)
  const unsigned char* za[4];
  #pragma unroll
  for (int mf = 0; mf < 4; ++mf){
    int m = m0 + mh * 64 + mf * 16 + lr;
    if (m >= M_) m = M_ - 1;
    za[mf] = z + (size_t)m * K1N + k0 + lq * 16;
  }

  const i32x4 zero4 = {0, 0, 0, 0};
  i32x4 accA[4][4], accB[4][4];
  #pragma unroll
  for (int mf = 0; mf < 4; ++mf)
    #pragma unroll
    for (int nf = 0; nf < 4; ++nf){ accA[mf][nf] = zero4; accB[mf][nf] = zero4; }

  uint4 pb[4];
  k2_loadB(wa, wb, k0, tid, pb);
  #pragma unroll
  for (int i = 0; i < 4; ++i){
    int idx = tid + 512 * i;
    int g = idx >> 2, c16 = idx & 3;
    *(uint4*)(&Bw[0][g * 80 + c16 * 16]) = pb[i];
  }

  #pragma unroll 1
  for (int kc = 0; kc < KCH; kc += BK2){
    const int cur = (kc >> 6) & 1;
    __syncthreads();                            // Bw[cur] published

    if (kc + BK2 < KCH) k2_loadB(wa, wb, k0 + kc + BK2, tid, pb);

    i32x4 af[4];
    #pragma unroll
    for (int mf = 0; mf < 4; ++mf)
      af[mf] = *(const i32x4*)(za[mf] + kc);    // global, L1-broadcast

    i32x4 ba[4], bbf[4];
    #pragma unroll
    for (int nf = 0; nf < 4; ++nf){
      ba[nf]  = *(const i32x4*)(&Bw[cur][(nq * 64 + nf * 16 + lr) * 80 + lq * 16]);
      bbf[nf] = *(const i32x4*)(&Bw[cur][(256 + nq * 64 + nf * 16 + lr) * 80 + lq * 16]);
    }
    #pragma unroll
    for (int mf = 0; mf < 4; ++mf)
      #pragma unroll
      for (int nf = 0; nf < 4; ++nf){
        accA[mf][nf] = __builtin_amdgcn_mfma_i32_16x16x64_i8(af[mf], ba[nf],  accA[mf][nf], 0, 0, 0);
        accB[mf][nf] = __builtin_amdgcn_mfma_i32_16x16x64_i8(af[mf], bbf[nf], accB[mf][nf], 0, 0, 0);
      }

    if (kc + BK2 < KCH){
      #pragma unroll
      for (int i = 0; i < 4; ++i){
        int idx = tid + 512 * i;
        int g = idx >> 2, c16 = idx & 3;
        *(uint4*)(&Bw[cur ^ 1][g * 80 + c16 * 16]) = pb[i];
      }
    }
  }

  // epilogue: C row = lq*4+reg (m), col = lr (n); combine exact int sums
  #pragma unroll
  for (int mf = 0; mf < 4; ++mf)
    #pragma unroll
    for (int nf = 0; nf < 4; ++nf)
      #pragma unroll
      for (int r = 0; r < 4; ++r){
        int m = m0 + mh * 64 + mf * 16 + lq * 4 + r;
        int n = nq * 64 + nf * 16 + lr;
        if (m < M_ && n < N2_)
          P[((size_t)ks * M_ + m) * N2_ + n] =
            fmaf((float)accA[mf][nf][r], 0x1p-14f, (float)accB[mf][nf][r] * 0x1p-22f);
      }
}

// ---------------------------------------------------------------- K2b: reduce k-splits
__global__ __launch_bounds__(256) void k2b_reduce(const float* __restrict__ P,
                                                  float* __restrict__ G2){
  int j = blockIdx.x * 256 + threadIdx.x;
  if (j >= M_ * N2_) return;
  float s = 0.f;
  #pragma unroll
  for (int ks = 0; ks < KSPL; ++ks) s += P[(size_t)ks * (M_ * N2_) + j];
  G2[j] = s;
}

// ---------------------------------------------------------------- K3: LIF2+FC2+LIF3 scan
__global__ __launch_bounds__(256) void k3_scan(const float* __restrict__ G2,
                                               const float* __restrict__ w2,
                                               float* __restrict__ out){
  const int b = blockIdx.x;
  const int tid = threadIdx.x;
  const float w = (tid < N2_) ? w2[tid] : 0.f;
  float m2 = 0.f, m3 = 0.f;
  __shared__ float part[4];

  float nxt = (tid < N2_) ? G2[(size_t)b * N2_ + tid] : 0.f;
  for (int t = 0; t < T_; ++t){
    float g2v = nxt;
    if (t < T_ - 1 && tid < N2_) nxt = G2[(size_t)((t + 1) * B_ + b) * N2_ + tid];
    float nm = (m2 > 1.0f) ? 0.f : __fadd_rn(__fmul_rn(0.9f, m2), g2v);
    m2 = nm;
    float s = (m2 > 1.0f) ? w : 0.f;
    #pragma unroll
    for (int off = 32; off > 0; off >>= 1) s += __shfl_down(s, off, 64);
    if ((tid & 63) == 0) part[tid >> 6] = s;
    __syncthreads();
    if (tid == 0){
      float g3 = (part[0] + part[1]) + (part[2] + part[3]);
      m3 = __fadd_rn(__fmul_rn(0.95f, m3), g3);
      out[b * T_ + t] = m3;
    }
    __syncthreads();
  }
}

// ---------------------------------------------------------------- host
extern "C" void kernel_launch(void* const* d_in, const int* in_sizes, int n_in,
                              void* d_out, int out_size, void* d_ws, size_t ws_size,
                              hipStream_t stream){
  const float* x    = (const float*)d_in[0];
  const float* kern = (const float*)d_in[1];
  const float* w1   = (const float*)d_in[2];
  const float* w2   = (const float*)d_in[3];
  float* out = (float*)d_out;

  char* p = (char*)d_ws;
  unsigned char* z8 = (unsigned char*)p;     p += (size_t)M_ * K1N;            // 52.4 MB
  char* wa = p;                              p += (size_t)NP_ * K1N;           // 16.8 MB
  char* wb = p;                              p += (size_t)NP_ * K1N;           // 16.8 MB
  float* P  = (float*)p;                     p += (size_t)KSPL * M_ * N2_ * 4; // 20.5 MB
  float* G2 = (float*)p;                     p += (size_t)M_ * N2_ * 4;        // 0.64 MB

  size_t need = (size_t)(p - (char*)d_ws);
  if (ws_size < need) return;

  hipLaunchKernelGGL(k01_fused,  dim3(NCONV + NPERM), dim3(256), 0, stream,
                     x, kern, w1, z8, wa, wb);
  hipLaunchKernelGGL(k2_gemm,    dim3(MT2 * KSPL), dim3(512), 0, stream, z8, wa, wb, P);
  hipLaunchKernelGGL(k2b_reduce, dim3((M_ * N2_ + 255) / 256), dim3(256), 0, stream, P, G2);
  hipLaunchKernelGGL(k3_scan,    dim3(B_), dim3(256), 0, stream, G2, w2, out);
}

// Round 13
// 137.647 us; speedup vs baseline: 1.0344x; 1.0344x over previous
//
#include <hip/hip_runtime.h>
#include <hip/hip_bf16.h>

// Motion-detection Gauss-LIF SNN:
//   K01 (fused, heterogeneous 256-thread blocks) — r10-proven form:
//     blocks [0,512):    conv(16x9x9) via MFMA bf16 16x16x32 + LIF1 ->
//                        Z1 [800][65536] i8 {0,1} in k'-order (SW=84,
//                        narrow wave-parity reads, separate limb arrays).
//     blocks [512,6912): w1 -> i8 (A,B) split, k'-permuted, conflict-free LDS.
//   K2: Z1 @ w1^T via two mfma_i32_16x16x64_i8 (exact i32). BM=128, KSPL=32,
//       XCD-chunked. A-fragments direct from global with ONE-ITERATION
//       REGISTER PREFETCH (latency hidden under MFMA phase); B double-buffered
//       in LDS with post-MFMA writes -> 1 barrier per k-step.
//   K2b: reduce partials; K3: sequential LIF2+FC2+LIF3 scan.
// LIF recurrences __fmul_rn/__fadd_rn (no contract). Deterministic order.

typedef __attribute__((ext_vector_type(8))) short short8;
typedef __attribute__((ext_vector_type(4))) float f32x4;
typedef __attribute__((ext_vector_type(4))) int   i32x4;

#define B_   16
#define T_   50
#define HW_  4096
#define K1N  65536
#define M_   800
#define N2_  200
#define NP_  256
#define KSPL 32
#define BM2  128
#define BK2  64
#define KCH  (K1N / KSPL)  // 2048
#define MT2  7             // ceil(800/128)
#define SW   84            // conv tile stride (ushorts), r7/r10-proven
#define TILE (12 * SW)     // 1008
#define NCONV 512
#define NPERM (200 * 32)

static __device__ __forceinline__ short8 mk8(uint a, uint b, uint c, uint d){
  union { uint u[4]; short8 v; } x;
  x.u[0] = a; x.u[1] = b; x.u[2] = c; x.u[3] = d;
  return x.v;
}
static __device__ __forceinline__ uint fnl(uint a, uint b){ return (a >> 16) | (b << 16); }

// ---------------------------------------------------------------- conv helpers (r7/r10)
template<bool WODD>
static __device__ __forceinline__ void rd5(const uint* p, int dw, uint e[5]){
  if (WODD){
    e[0] = p[dw];
    uint2 a = *(const uint2*)(p + dw + 1);
    uint2 b = *(const uint2*)(p + dw + 3);
    e[1] = a.x; e[2] = a.y; e[3] = b.x; e[4] = b.y;
  } else {
    uint2 a = *(const uint2*)(p + dw);
    uint2 b = *(const uint2*)(p + dw + 2);
    e[0] = a.x; e[1] = a.y; e[2] = b.x; e[3] = b.y;
    e[4] = p[dw + 4];
  }
}

template<bool WODD>
static __device__ __forceinline__ void conv_phase(const uint* T0, const uint* T1,
                                                  int bdw,
                                                  const short8 (&afh)[5],
                                                  const short8 (&afl)[5],
                                                  f32x4& acc0, f32x4& acc1){
  #pragma unroll
  for (int ks = 0; ks < 5; ++ks){
    const int dw = bdw + (SW / 2) * 2 * ks;   // +84 dwords per kstep (2 rows)
    uint h[5], m[5];
    rd5<WODD>(T0, dw, h);
    rd5<WODD>(T1, dw, m);
    short8 bh0 = mk8(h[0], h[1], h[2], h[3]);
    short8 bm0 = mk8(m[0], m[1], m[2], m[3]);
    acc0 = __builtin_amdgcn_mfma_f32_16x16x32_bf16(afh[ks], bh0, acc0, 0, 0, 0);
    acc0 = __builtin_amdgcn_mfma_f32_16x16x32_bf16(afh[ks], bm0, acc0, 0, 0, 0);
    acc0 = __builtin_amdgcn_mfma_f32_16x16x32_bf16(afl[ks], bh0, acc0, 0, 0, 0);
    short8 bh1 = mk8(fnl(h[0], h[1]), fnl(h[1], h[2]), fnl(h[2], h[3]), fnl(h[3], h[4]));
    short8 bm1 = mk8(fnl(m[0], m[1]), fnl(m[1], m[2]), fnl(m[2], m[3]), fnl(m[3], m[4]));
    acc1 = __builtin_amdgcn_mfma_f32_16x16x32_bf16(afh[ks], bh1, acc1, 0, 0, 0);
    acc1 = __builtin_amdgcn_mfma_f32_16x16x32_bf16(afh[ks], bm1, acc1, 0, 0, 0);
    acc1 = __builtin_amdgcn_mfma_f32_16x16x32_bf16(afl[ks], bh1, acc1, 0, 0, 0);
  }
}

static __device__ __forceinline__ void stage_tile(ushort* Th, ushort* Tm,
                                                  int eb, float4 f){
  float vv[4] = {f.x, f.y, f.z, f.w};
  ushort sh[4], sm[4];
  #pragma unroll
  for (int ii = 0; ii < 4; ++ii){
    __hip_bfloat16 h = __float2bfloat16(vv[ii]);
    float t1 = vv[ii] - __bfloat162float(h);
    __hip_bfloat16 m = __float2bfloat16(t1);
    sh[ii] = *reinterpret_cast<ushort*>(&h);
    sm[ii] = *reinterpret_cast<ushort*>(&m);
  }
  *(ushort4*)(Th + eb) = make_ushort4(sh[0], sh[1], sh[2], sh[3]);
  *(ushort4*)(Tm + eb) = make_ushort4(sm[0], sm[1], sm[2], sm[3]);
}

// ---------------------------------------------------------------- K01 (r10 verbatim)
__global__ __launch_bounds__(256) void k01_fused(const float* __restrict__ x,
                                                 const float* __restrict__ kern,
                                                 const float* __restrict__ w1,
                                                 unsigned char* __restrict__ zout,
                                                 char* __restrict__ wa,
                                                 char* __restrict__ wb){
  __shared__ __align__(16) ushort smem[9152];
  const int bid = blockIdx.x;
  const int tid = threadIdx.x;

  if (bid >= NCONV){
    // ---------------- w1 -> i8 (A,B) split + k'-permute, conflict-free ------
    uint* la = (uint*)smem;               // 520 uints (o-padded)
    uint* lb = ((uint*)smem) + 528;
    const int bid2 = bid - NCONV;
    const int n = bid2 >> 5;
    const int strip = bid2 & 31;
    const int p128 = tid & 127;
    const int qp   = tid >> 7;            // 0 or 1
    const int o = p128 & 7, s = p128 >> 3;
    const float* src = w1 + (size_t)n * K1N + strip * 128 + p128;
    #pragma unroll
    for (int qi = 0; qi < 2; ++qi){
      const int q = 2 * qp + qi;
      uint ua = 0, ub = 0;
      #pragma unroll
      for (int r = 0; r < 4; ++r){
        float v = src[(size_t)(4 * q + r) * 4096];
        float af = rintf(v * 16384.f);     // |af| <= 64
        float rr = v - af * 0x1p-14f;      // exact (Sterbenz)
        float bf = rintf(rr * 0x1p22f);    // in [-128, 128]
        int A = (int)af, Bq = (int)bf;
        if (Bq == 128){ A += 1; Bq = -128; }
        ua |= ((uint)(A & 255))  << (8 * r);
        ub |= ((uint)(Bq & 255)) << (8 * r);
      }
      const int u = 64 * o + 4 * s + q + o;   // +o pad -> <=2-way (free)
      la[u] = ua;
      lb[u] = ub;
    }
    __syncthreads();
    {
      const int j0 = 2 * tid;               // 0..510
      const int o2 = j0 >> 6;
      uint a0 = la[j0 + o2], a1 = la[j0 + 1 + o2];
      uint b0 = lb[j0 + o2], b1 = lb[j0 + 1 + o2];
      const size_t ob = (size_t)n * K1N + strip * 2048 + (size_t)j0 * 4;
      *(uint2*)(wa + ob) = make_uint2(a0, a1);
      *(uint2*)(wb + ob) = make_uint2(b0, b1);
    }
    return;
  }

  // ---------------- conv + LIF1 path (r10 verbatim) ----------------
  ushort* Ah  = smem;
  ushort* Alo = smem + 2560;
  ushort* Tt  = smem + 5120;               // [buf][limb][TILE]

  const int strip = bid & 31;
  const int b = bid >> 5;
  const int w = tid >> 6;
  const int l = tid & 63;
  const int q = l >> 4;
  const int s = l & 15;

  for (int slot = tid; slot < 16 * 160; slot += 256){
    int ch = slot / 160, kk = slot - ch * 160;
    int dy = kk >> 4, dx = kk & 15;
    float v = 0.f;
    if (dy < 9 && dx < 9) v = kern[ch * 81 + dy * 9 + dx];
    __hip_bfloat16 h = __float2bfloat16(v);
    float hf = __bfloat162float(h);
    __hip_bfloat16 lo = __float2bfloat16(v - hf);
    Ah[slot]  = *reinterpret_cast<ushort*>(&h);
    Alo[slot] = *reinterpret_cast<ushort*>(&lo);
  }

  const bool sact = tid < 240;
  const int sr = tid / 20, sc4 = tid - sr * 20;
  const int r0 = 2 * strip - 4;
  const int imr = r0 + sr;
  const bool sin = sact && imr >= 0 && imr < 64 && sc4 >= 1 && sc4 <= 16;
  const float* xb = x + (size_t)b * (T_ * HW_);
  const float* xsrc = xb + (sin ? (imr * 64 + (sc4 - 1) * 4) : 0);
  const int eb = sr * SW + sc4 * 4;

  {
    float4 f0 = make_float4(0.f, 0.f, 0.f, 0.f);
    if (sin) f0 = *(const float4*)(xsrc);
    if (sact) stage_tile(Tt + 0 * TILE, Tt + 1 * TILE, eb, f0);
  }
  __syncthreads();

  short8 afh[5], afl[5];
  #pragma unroll
  for (int ks = 0; ks < 5; ++ks){
    afh[ks] = *(const short8*)(Ah + s * 160 + ks * 32 + q * 8);
    afl[ks] = *(const short8*)(Alo + s * 160 + ks * 32 + q * 8);
  }

  const int p0 = (s >> 3) + (q >> 1);
  const int bdw = 42 * p0 + 4 * (s & 7) + 4 * (q & 1) + w;
  const bool wodd = (w & 1) != 0;

  float m1v[2][4];
  #pragma unroll
  for (int oi = 0; oi < 2; ++oi)
    #pragma unroll
    for (int r = 0; r < 4; ++r) m1v[oi][r] = 0.f;

  for (int t = 0; t < T_; ++t){
    __syncthreads();                           // tile t&1 ready
    float4 nfx = make_float4(0.f, 0.f, 0.f, 0.f);
    if (t + 1 < T_ && sin) nfx = *(const float4*)(xsrc + (size_t)(t + 1) * HW_);

    const int bb = t & 1;
    const uint* T0 = (const uint*)(Tt + (bb * 2 + 0) * TILE);
    const uint* T1 = (const uint*)(Tt + (bb * 2 + 1) * TILE);
    f32x4 acc0 = (f32x4)(0.f), acc1 = (f32x4)(0.f);
    if (wodd) conv_phase<true >(T0, T1, bdw, afh, afl, acc0, acc1);
    else      conv_phase<false>(T0, T1, bdw, afh, afl, acc0, acc1);

    const size_t zr = ((size_t)(t * B_ + b)) * K1N + strip * 2048 + s * 16 + q * 4;
    {
      uint zw = 0;
      #pragma unroll
      for (int r = 0; r < 4; ++r){
        float m = m1v[0][r];
        float nm = (m > 1.0f) ? 0.0f : __fadd_rn(__fmul_rn(0.9f, m), acc0[r]);
        m1v[0][r] = nm;
        if (nm > 1.0f) zw |= (1u << (8 * r));
      }
      *(uint*)(zout + zr + (size_t)(2 * w) * 256) = zw;
    }
    {
      uint zw = 0;
      #pragma unroll
      for (int r = 0; r < 4; ++r){
        float m = m1v[1][r];
        float nm = (m > 1.0f) ? 0.0f : __fadd_rn(__fmul_rn(0.9f, m), acc1[r]);
        m1v[1][r] = nm;
        if (nm > 1.0f) zw |= (1u << (8 * r));
      }
      *(uint*)(zout + zr + (size_t)(2 * w + 1) * 256) = zw;
    }

    if (t + 1 < T_ && sact)
      stage_tile(Tt + ((bb ^ 1) * 2 + 0) * TILE, Tt + ((bb ^ 1) * 2 + 1) * TILE, eb, nfx);
  }
}

// ---------------------------------------------------------------- K2 B-loader (i8)
static __device__ __forceinline__ void k2_loadB(const char* __restrict__ wa,
                                                const char* __restrict__ wb,
                                                int kg, int tid, uint4 pb[4]){
  #pragma unroll
  for (int i = 0; i < 4; ++i){
    int idx = tid + 512 * i;               // 0..2047
    int g   = idx >> 2;                    // row 0..511
    int c16 = idx & 3;
    int sel = g >> 8;
    int r   = g & 255;
    const char* src = sel ? wb : wa;
    pb[i] = make_uint4(0, 0, 0, 0);
    if (r < N2_) pb[i] = *(const uint4*)(src + (size_t)r * K1N + kg + c16 * 16);
  }
}

// ---------------------------------------------------------------- K2: i8 MFMA GEMM
// grid 224 = m-tile(7 x 128) x k-split(32 x 2048); block 512 = 8 waves.
// A direct from global with 1-iter register prefetch (latency hidden under
// MFMA phase); B double-buffered, writes post-MFMA, 1 barrier per k-step.
__global__ __launch_bounds__(512) void k2_gemm(const unsigned char* __restrict__ z,
                                               const char* __restrict__ wa,
                                               const char* __restrict__ wb,
                                               float* __restrict__ P){
  __shared__ __align__(16) unsigned char Bw[2][512 * 80];

  const int bid = blockIdx.x;
  const int L = (bid & 7) * 28 + (bid >> 3);      // bijective: 224 = 8*28
  const int ks = L / MT2;
  const int mt = L % MT2;
  const int m0 = mt * BM2;
  const int k0 = ks * KCH;
  const int tid = threadIdx.x;
  const int wv = tid >> 6;
  const int mh = wv >> 2;
  const int nq = wv & 3;
  const int l  = tid & 63;
  const int lr = l & 15;
  const int lq = l >> 4;

  // per-lane A row pointers (clamped; epilogue guards m < M_)
  const unsigned char* za[4];
  #pragma unroll
  for (int mf = 0; mf < 4; ++mf){
    int m = m0 + mh * 64 + mf * 16 + lr;
    if (m >= M_) m = M_ - 1;
    za[mf] = z + (size_t)m * K1N + k0 + lq * 16;
  }

  const i32x4 zero4 = {0, 0, 0, 0};
  i32x4 accA[4][4], accB[4][4];
  #pragma unroll
  for (int mf = 0; mf < 4; ++mf)
    #pragma unroll
    for (int nf = 0; nf < 4; ++nf){ accA[mf][nf] = zero4; accB[mf][nf] = zero4; }

  // prologue: B tile 0 -> LDS, A frags for kc=0 -> regs
  uint4 pb[4];
  k2_loadB(wa, wb, k0, tid, pb);
  i32x4 af[4], afn[4];
  #pragma unroll
  for (int mf = 0; mf < 4; ++mf) af[mf] = *(const i32x4*)(za[mf]);
  #pragma unroll
  for (int i = 0; i < 4; ++i){
    int idx = tid + 512 * i;
    int g = idx >> 2, c16 = idx & 3;
    *(uint4*)(&Bw[0][g * 80 + c16 * 16]) = pb[i];
  }

  #pragma unroll 1
  for (int kc = 0; kc < KCH; kc += BK2){
    const int cur = (kc >> 6) & 1;
    __syncthreads();                            // Bw[cur] published

    const bool more = (kc + BK2 < KCH);
    if (more){
      k2_loadB(wa, wb, k0 + kc + BK2, tid, pb); // vmem, lands post-MFMA
      #pragma unroll
      for (int mf = 0; mf < 4; ++mf)
        afn[mf] = *(const i32x4*)(za[mf] + kc + BK2);  // vmem, used next iter
    }

    i32x4 ba[4], bbf[4];
    #pragma unroll
    for (int nf = 0; nf < 4; ++nf){
      ba[nf]  = *(const i32x4*)(&Bw[cur][(nq * 64 + nf * 16 + lr) * 80 + lq * 16]);
      bbf[nf] = *(const i32x4*)(&Bw[cur][(256 + nq * 64 + nf * 16 + lr) * 80 + lq * 16]);
    }
    #pragma unroll
    for (int mf = 0; mf < 4; ++mf)
      #pragma unroll
      for (int nf = 0; nf < 4; ++nf){
        accA[mf][nf] = __builtin_amdgcn_mfma_i32_16x16x64_i8(af[mf], ba[nf],  accA[mf][nf], 0, 0, 0);
        accB[mf][nf] = __builtin_amdgcn_mfma_i32_16x16x64_i8(af[mf], bbf[nf], accB[mf][nf], 0, 0, 0);
      }

    if (more){
      #pragma unroll
      for (int i = 0; i < 4; ++i){
        int idx = tid + 512 * i;
        int g = idx >> 2, c16 = idx & 3;
        *(uint4*)(&Bw[cur ^ 1][g * 80 + c16 * 16]) = pb[i];
      }
      #pragma unroll
      for (int mf = 0; mf < 4; ++mf) af[mf] = afn[mf];
    }
  }

  // epilogue: C row = lq*4+reg (m), col = lr (n); combine exact int sums
  #pragma unroll
  for (int mf = 0; mf < 4; ++mf)
    #pragma unroll
    for (int nf = 0; nf < 4; ++nf)
      #pragma unroll
      for (int r = 0; r < 4; ++r){
        int m = m0 + mh * 64 + mf * 16 + lq * 4 + r;
        int n = nq * 64 + nf * 16 + lr;
        if (m < M_ && n < N2_)
          P[((size_t)ks * M_ + m) * N2_ + n] =
            fmaf((float)accA[mf][nf][r], 0x1p-14f, (float)accB[mf][nf][r] * 0x1p-22f);
      }
}

// ---------------------------------------------------------------- K2b: reduce k-splits
__global__ __launch_bounds__(256) void k2b_reduce(const float* __restrict__ P,
                                                  float* __restrict__ G2){
  int j = blockIdx.x * 256 + threadIdx.x;
  if (j >= M_ * N2_) return;
  float s = 0.f;
  #pragma unroll
  for (int ks = 0; ks < KSPL; ++ks) s += P[(size_t)ks * (M_ * N2_) + j];
  G2[j] = s;
}

// ---------------------------------------------------------------- K3: LIF2+FC2+LIF3 scan
__global__ __launch_bounds__(256) void k3_scan(const float* __restrict__ G2,
                                               const float* __restrict__ w2,
                                               float* __restrict__ out){
  const int b = blockIdx.x;
  const int tid = threadIdx.x;
  const float w = (tid < N2_) ? w2[tid] : 0.f;
  float m2 = 0.f, m3 = 0.f;
  __shared__ float part[4];

  float nxt = (tid < N2_) ? G2[(size_t)b * N2_ + tid] : 0.f;
  for (int t = 0; t < T_; ++t){
    float g2v = nxt;
    if (t < T_ - 1 && tid < N2_) nxt = G2[(size_t)((t + 1) * B_ + b) * N2_ + tid];
    float nm = (m2 > 1.0f) ? 0.f : __fadd_rn(__fmul_rn(0.9f, m2), g2v);
    m2 = nm;
    float s = (m2 > 1.0f) ? w : 0.f;
    #pragma unroll
    for (int off = 32; off > 0; off >>= 1) s += __shfl_down(s, off, 64);
    if ((tid & 63) == 0) part[tid >> 6] = s;
    __syncthreads();
    if (tid == 0){
      float g3 = (part[0] + part[1]) + (part[2] + part[3]);
      m3 = __fadd_rn(__fmul_rn(0.95f, m3), g3);
      out[b * T_ + t] = m3;
    }
    __syncthreads();
  }
}

// ---------------------------------------------------------------- host
extern "C" void kernel_launch(void* const* d_in, const int* in_sizes, int n_in,
                              void* d_out, int out_size, void* d_ws, size_t ws_size,
                              hipStream_t stream){
  const float* x    = (const float*)d_in[0];
  const float* kern = (const float*)d_in[1];
  const float* w1   = (const float*)d_in[2];
  const float* w2   = (const float*)d_in[3];
  float* out = (float*)d_out;

  char* p = (char*)d_ws;
  unsigned char* z8 = (unsigned char*)p;     p += (size_t)M_ * K1N;            // 52.4 MB
  char* wa = p;                              p += (size_t)NP_ * K1N;           // 16.8 MB
  char* wb = p;                              p += (size_t)NP_ * K1N;           // 16.8 MB
  float* P  = (float*)p;                     p += (size_t)KSPL * M_ * N2_ * 4; // 20.5 MB
  float* G2 = (float*)p;                     p += (size_t)M_ * N2_ * 4;        // 0.64 MB

  size_t need = (size_t)(p - (char*)d_ws);
  if (ws_size < need) return;

  hipLaunchKernelGGL(k01_fused,  dim3(NCONV + NPERM), dim3(256), 0, stream,
                     x, kern, w1, z8, wa, wb);
  hipLaunchKernelGGL(k2_gemm,    dim3(MT2 * KSPL), dim3(512), 0, stream, z8, wa, wb, P);
  hipLaunchKernelGGL(k2b_reduce, dim3((M_ * N2_ + 255) / 256), dim3(256), 0, stream, P, G2);
  hipLaunchKernelGGL(k3_scan,    dim3(B_), dim3(256), 0, stream, G2, w2, out);
}

// Round 14
// 126.315 us; speedup vs baseline: 1.1272x; 1.0897x over previous
//
#include <hip/hip_runtime.h>
#include <hip/hip_bf16.h>

// Motion-detection Gauss-LIF SNN:
//   K01 (fused, heterogeneous 256-thread blocks) — r10-proven form:
//     blocks [0,512):    conv(16x9x9) via MFMA bf16 16x16x32 + LIF1 ->
//                        Z1 [800][65536] i8 {0,1} in k'-order (SW=84,
//                        narrow wave-parity reads, separate limb arrays).
//     blocks [512,6912): w1 -> i8 (A,B) split, k'-permuted, conflict-free LDS.
//   K2: Z1 @ w1^T via two mfma_i32_16x16x64_i8 (exact i32). BM=128, KSPL=32,
//       N SPLIT IN 2 HALVES (100 cols, padded 128) -> grid 448 (~14 waves/CU
//       vs r10's 8), B tile halved (11 DS ops/thread/iter vs 17). A staged in
//       LDS (r10-proven), register prefetch of next tile. XCD-chunked.
//   K2b: reduce partials; K3: sequential LIF2+FC2+LIF3 scan.
// LIF recurrences __fmul_rn/__fadd_rn (no contract). Deterministic order.

typedef __attribute__((ext_vector_type(8))) short short8;
typedef __attribute__((ext_vector_type(4))) float f32x4;
typedef __attribute__((ext_vector_type(4))) int   i32x4;

#define B_   16
#define T_   50
#define HW_  4096
#define K1N  65536
#define M_   800
#define N2_  200
#define NP_  256
#define KSPL 32
#define BM2  128
#define BK2  64
#define KCH  (K1N / KSPL)  // 2048
#define MT2  7             // ceil(800/128)
#define NHW  100           // real n per half
#define SW   84            // conv tile stride (ushorts), r7/r10-proven
#define TILE (12 * SW)     // 1008
#define NCONV 512
#define NPERM (200 * 32)

static __device__ __forceinline__ short8 mk8(uint a, uint b, uint c, uint d){
  union { uint u[4]; short8 v; } x;
  x.u[0] = a; x.u[1] = b; x.u[2] = c; x.u[3] = d;
  return x.v;
}
static __device__ __forceinline__ uint fnl(uint a, uint b){ return (a >> 16) | (b << 16); }

// ---------------------------------------------------------------- conv helpers (r7/r10)
template<bool WODD>
static __device__ __forceinline__ void rd5(const uint* p, int dw, uint e[5]){
  if (WODD){
    e[0] = p[dw];
    uint2 a = *(const uint2*)(p + dw + 1);
    uint2 b = *(const uint2*)(p + dw + 3);
    e[1] = a.x; e[2] = a.y; e[3] = b.x; e[4] = b.y;
  } else {
    uint2 a = *(const uint2*)(p + dw);
    uint2 b = *(const uint2*)(p + dw + 2);
    e[0] = a.x; e[1] = a.y; e[2] = b.x; e[3] = b.y;
    e[4] = p[dw + 4];
  }
}

template<bool WODD>
static __device__ __forceinline__ void conv_phase(const uint* T0, const uint* T1,
                                                  int bdw,
                                                  const short8 (&afh)[5],
                                                  const short8 (&afl)[5],
                                                  f32x4& acc0, f32x4& acc1){
  #pragma unroll
  for (int ks = 0; ks < 5; ++ks){
    const int dw = bdw + (SW / 2) * 2 * ks;   // +84 dwords per kstep (2 rows)
    uint h[5], m[5];
    rd5<WODD>(T0, dw, h);
    rd5<WODD>(T1, dw, m);
    short8 bh0 = mk8(h[0], h[1], h[2], h[3]);
    short8 bm0 = mk8(m[0], m[1], m[2], m[3]);
    acc0 = __builtin_amdgcn_mfma_f32_16x16x32_bf16(afh[ks], bh0, acc0, 0, 0, 0);
    acc0 = __builtin_amdgcn_mfma_f32_16x16x32_bf16(afh[ks], bm0, acc0, 0, 0, 0);
    acc0 = __builtin_amdgcn_mfma_f32_16x16x32_bf16(afl[ks], bh0, acc0, 0, 0, 0);
    short8 bh1 = mk8(fnl(h[0], h[1]), fnl(h[1], h[2]), fnl(h[2], h[3]), fnl(h[3], h[4]));
    short8 bm1 = mk8(fnl(m[0], m[1]), fnl(m[1], m[2]), fnl(m[2], m[3]), fnl(m[3], m[4]));
    acc1 = __builtin_amdgcn_mfma_f32_16x16x32_bf16(afh[ks], bh1, acc1, 0, 0, 0);
    acc1 = __builtin_amdgcn_mfma_f32_16x16x32_bf16(afh[ks], bm1, acc1, 0, 0, 0);
    acc1 = __builtin_amdgcn_mfma_f32_16x16x32_bf16(afl[ks], bh1, acc1, 0, 0, 0);
  }
}

static __device__ __forceinline__ void stage_tile(ushort* Th, ushort* Tm,
                                                  int eb, float4 f){
  float vv[4] = {f.x, f.y, f.z, f.w};
  ushort sh[4], sm[4];
  #pragma unroll
  for (int ii = 0; ii < 4; ++ii){
    __hip_bfloat16 h = __float2bfloat16(vv[ii]);
    float t1 = vv[ii] - __bfloat162float(h);
    __hip_bfloat16 m = __float2bfloat16(t1);
    sh[ii] = *reinterpret_cast<ushort*>(&h);
    sm[ii] = *reinterpret_cast<ushort*>(&m);
  }
  *(ushort4*)(Th + eb) = make_ushort4(sh[0], sh[1], sh[2], sh[3]);
  *(ushort4*)(Tm + eb) = make_ushort4(sm[0], sm[1], sm[2], sm[3]);
}

// ---------------------------------------------------------------- K01 (r10 verbatim)
__global__ __launch_bounds__(256) void k01_fused(const float* __restrict__ x,
                                                 const float* __restrict__ kern,
                                                 const float* __restrict__ w1,
                                                 unsigned char* __restrict__ zout,
                                                 char* __restrict__ wa,
                                                 char* __restrict__ wb){
  __shared__ __align__(16) ushort smem[9152];
  const int bid = blockIdx.x;
  const int tid = threadIdx.x;

  if (bid >= NCONV){
    // ---------------- w1 -> i8 (A,B) split + k'-permute, conflict-free ------
    uint* la = (uint*)smem;               // 520 uints (o-padded)
    uint* lb = ((uint*)smem) + 528;
    const int bid2 = bid - NCONV;
    const int n = bid2 >> 5;
    const int strip = bid2 & 31;
    const int p128 = tid & 127;
    const int qp   = tid >> 7;            // 0 or 1
    const int o = p128 & 7, s = p128 >> 3;
    const float* src = w1 + (size_t)n * K1N + strip * 128 + p128;
    #pragma unroll
    for (int qi = 0; qi < 2; ++qi){
      const int q = 2 * qp + qi;
      uint ua = 0, ub = 0;
      #pragma unroll
      for (int r = 0; r < 4; ++r){
        float v = src[(size_t)(4 * q + r) * 4096];
        float af = rintf(v * 16384.f);     // |af| <= 64
        float rr = v - af * 0x1p-14f;      // exact (Sterbenz)
        float bf = rintf(rr * 0x1p22f);    // in [-128, 128]
        int A = (int)af, Bq = (int)bf;
        if (Bq == 128){ A += 1; Bq = -128; }
        ua |= ((uint)(A & 255))  << (8 * r);
        ub |= ((uint)(Bq & 255)) << (8 * r);
      }
      const int u = 64 * o + 4 * s + q + o;   // +o pad -> <=2-way (free)
      la[u] = ua;
      lb[u] = ub;
    }
    __syncthreads();
    {
      const int j0 = 2 * tid;               // 0..510
      const int o2 = j0 >> 6;
      uint a0 = la[j0 + o2], a1 = la[j0 + 1 + o2];
      uint b0 = lb[j0 + o2], b1 = lb[j0 + 1 + o2];
      const size_t ob = (size_t)n * K1N + strip * 2048 + (size_t)j0 * 4;
      *(uint2*)(wa + ob) = make_uint2(a0, a1);
      *(uint2*)(wb + ob) = make_uint2(b0, b1);
    }
    return;
  }

  // ---------------- conv + LIF1 path (r10 verbatim) ----------------
  ushort* Ah  = smem;
  ushort* Alo = smem + 2560;
  ushort* Tt  = smem + 5120;               // [buf][limb][TILE]

  const int strip = bid & 31;
  const int b = bid >> 5;
  const int w = tid >> 6;
  const int l = tid & 63;
  const int q = l >> 4;
  const int s = l & 15;

  for (int slot = tid; slot < 16 * 160; slot += 256){
    int ch = slot / 160, kk = slot - ch * 160;
    int dy = kk >> 4, dx = kk & 15;
    float v = 0.f;
    if (dy < 9 && dx < 9) v = kern[ch * 81 + dy * 9 + dx];
    __hip_bfloat16 h = __float2bfloat16(v);
    float hf = __bfloat162float(h);
    __hip_bfloat16 lo = __float2bfloat16(v - hf);
    Ah[slot]  = *reinterpret_cast<ushort*>(&h);
    Alo[slot] = *reinterpret_cast<ushort*>(&lo);
  }

  const bool sact = tid < 240;
  const int sr = tid / 20, sc4 = tid - sr * 20;
  const int r0 = 2 * strip - 4;
  const int imr = r0 + sr;
  const bool sin = sact && imr >= 0 && imr < 64 && sc4 >= 1 && sc4 <= 16;
  const float* xb = x + (size_t)b * (T_ * HW_);
  const float* xsrc = xb + (sin ? (imr * 64 + (sc4 - 1) * 4) : 0);
  const int eb = sr * SW + sc4 * 4;

  {
    float4 f0 = make_float4(0.f, 0.f, 0.f, 0.f);
    if (sin) f0 = *(const float4*)(xsrc);
    if (sact) stage_tile(Tt + 0 * TILE, Tt + 1 * TILE, eb, f0);
  }
  __syncthreads();

  short8 afh[5], afl[5];
  #pragma unroll
  for (int ks = 0; ks < 5; ++ks){
    afh[ks] = *(const short8*)(Ah + s * 160 + ks * 32 + q * 8);
    afl[ks] = *(const short8*)(Alo + s * 160 + ks * 32 + q * 8);
  }

  const int p0 = (s >> 3) + (q >> 1);
  const int bdw = 42 * p0 + 4 * (s & 7) + 4 * (q & 1) + w;
  const bool wodd = (w & 1) != 0;

  float m1v[2][4];
  #pragma unroll
  for (int oi = 0; oi < 2; ++oi)
    #pragma unroll
    for (int r = 0; r < 4; ++r) m1v[oi][r] = 0.f;

  for (int t = 0; t < T_; ++t){
    __syncthreads();                           // tile t&1 ready
    float4 nfx = make_float4(0.f, 0.f, 0.f, 0.f);
    if (t + 1 < T_ && sin) nfx = *(const float4*)(xsrc + (size_t)(t + 1) * HW_);

    const int bb = t & 1;
    const uint* T0 = (const uint*)(Tt + (bb * 2 + 0) * TILE);
    const uint* T1 = (const uint*)(Tt + (bb * 2 + 1) * TILE);
    f32x4 acc0 = (f32x4)(0.f), acc1 = (f32x4)(0.f);
    if (wodd) conv_phase<true >(T0, T1, bdw, afh, afl, acc0, acc1);
    else      conv_phase<false>(T0, T1, bdw, afh, afl, acc0, acc1);

    const size_t zr = ((size_t)(t * B_ + b)) * K1N + strip * 2048 + s * 16 + q * 4;
    {
      uint zw = 0;
      #pragma unroll
      for (int r = 0; r < 4; ++r){
        float m = m1v[0][r];
        float nm = (m > 1.0f) ? 0.0f : __fadd_rn(__fmul_rn(0.9f, m), acc0[r]);
        m1v[0][r] = nm;
        if (nm > 1.0f) zw |= (1u << (8 * r));
      }
      *(uint*)(zout + zr + (size_t)(2 * w) * 256) = zw;
    }
    {
      uint zw = 0;
      #pragma unroll
      for (int r = 0; r < 4; ++r){
        float m = m1v[1][r];
        float nm = (m > 1.0f) ? 0.0f : __fadd_rn(__fmul_rn(0.9f, m), acc1[r]);
        m1v[1][r] = nm;
        if (nm > 1.0f) zw |= (1u << (8 * r));
      }
      *(uint*)(zout + zr + (size_t)(2 * w + 1) * 256) = zw;
    }

    if (t + 1 < T_ && sact)
      stage_tile(Tt + ((bb ^ 1) * 2 + 0) * TILE, Tt + ((bb ^ 1) * 2 + 1) * TILE, eb, nfx);
  }
}

// ---------------------------------------------------------------- K2 prefetch loader (i8)
// A: 128 rows x 64 k (512 x uint4); B half: 256 rows (wa 0-127, wb 128-255)
static __device__ __forceinline__ void k2_load(const unsigned char* __restrict__ z,
                                               const char* __restrict__ wa,
                                               const char* __restrict__ wb,
                                               int m0, int n0, int kg, int tid,
                                               uint4& pa, uint4 pb[2]){
  {
    int row = tid >> 2, c16 = tid & 3;
    int m = m0 + row;
    pa = make_uint4(0, 0, 0, 0);
    if (m < M_) pa = *(const uint4*)(z + (size_t)m * K1N + kg + c16 * 16);
  }
  #pragma unroll
  for (int i = 0; i < 2; ++i){
    int idx = tid + 512 * i;               // 0..1023
    int g   = idx >> 2;                    // 0..255
    int c16 = idx & 3;
    int sel = g >> 7;
    int rh  = g & 127;
    const char* src = sel ? wb : wa;
    pb[i] = make_uint4(0, 0, 0, 0);
    if (rh < NHW) pb[i] = *(const uint4*)(src + (size_t)(n0 + rh) * K1N + kg + c16 * 16);
  }
}

// ---------------------------------------------------------------- K2: i8 MFMA GEMM
// grid 448 = 8 XCDs x (ks(4) x mt(7) x nh(2)); block 512 = 8 waves
// (2 m-halves x 4 n-quads of 32). N split in 2 halves of 100 (padded 128).
__global__ __launch_bounds__(512) void k2_gemm(const unsigned char* __restrict__ z,
                                               const char* __restrict__ wa,
                                               const char* __restrict__ wb,
                                               float* __restrict__ P){
  __shared__ __align__(16) unsigned char Al[128 * 80];   // 10240 B
  __shared__ __align__(16) unsigned char Bw[256 * 80];   // 20480 B

  const int bid = blockIdx.x;
  const int L = (bid & 7) * 56 + (bid >> 3);      // bijective: 448 = 8*56
  const int ks = L / 14;                           // 0..31 (4 per XCD)
  const int rem = L % 14;
  const int mt = rem >> 1;
  const int nh = rem & 1;
  const int m0 = mt * BM2;
  const int n0 = nh * NHW;
  const int k0 = ks * KCH;
  const int tid = threadIdx.x;
  const int wv = tid >> 6;
  const int mh = wv >> 2;         // m-half (64 rows)
  const int nq = wv & 3;          // n-quad (32 cols)
  const int l  = tid & 63;
  const int lr = l & 15;
  const int lq = l >> 4;

  const i32x4 zero4 = {0, 0, 0, 0};
  i32x4 accA[4][2], accB[4][2];
  #pragma unroll
  for (int mf = 0; mf < 4; ++mf)
    #pragma unroll
    for (int nf = 0; nf < 2; ++nf){ accA[mf][nf] = zero4; accB[mf][nf] = zero4; }

  uint4 pa, pb[2];
  k2_load(z, wa, wb, m0, n0, k0, tid, pa, pb);

  #pragma unroll 1
  for (int kc = 0; kc < KCH; kc += BK2){
    // write prefetched tile to LDS
    {
      int row = tid >> 2, c16 = tid & 3;
      *(uint4*)(Al + row * 80 + c16 * 16) = pa;
    }
    #pragma unroll
    for (int i = 0; i < 2; ++i){
      int idx = tid + 512 * i;
      int g = idx >> 2, c16 = idx & 3;
      *(uint4*)(Bw + g * 80 + c16 * 16) = pb[i];
    }
    __syncthreads();

    // issue next tile's global loads (hidden under MFMA phase)
    if (kc + BK2 < KCH) k2_load(z, wa, wb, m0, n0, k0 + kc + BK2, tid, pa, pb);

    i32x4 af[4], ba[2], bbf[2];
    #pragma unroll
    for (int mf = 0; mf < 4; ++mf)
      af[mf] = *(const i32x4*)(Al + (mh * 64 + mf * 16 + lr) * 80 + lq * 16);
    #pragma unroll
    for (int nf = 0; nf < 2; ++nf){
      ba[nf]  = *(const i32x4*)(Bw + (nq * 32 + nf * 16 + lr) * 80 + lq * 16);
      bbf[nf] = *(const i32x4*)(Bw + (128 + nq * 32 + nf * 16 + lr) * 80 + lq * 16);
    }
    #pragma unroll
    for (int mf = 0; mf < 4; ++mf)
      #pragma unroll
      for (int nf = 0; nf < 2; ++nf){
        accA[mf][nf] = __builtin_amdgcn_mfma_i32_16x16x64_i8(af[mf], ba[nf],  accA[mf][nf], 0, 0, 0);
        accB[mf][nf] = __builtin_amdgcn_mfma_i32_16x16x64_i8(af[mf], bbf[nf], accB[mf][nf], 0, 0, 0);
      }
    __syncthreads();
  }

  // epilogue: C row = lq*4+reg (m), col = lr (n); combine exact int sums
  #pragma unroll
  for (int mf = 0; mf < 4; ++mf)
    #pragma unroll
    for (int nf = 0; nf < 2; ++nf)
      #pragma unroll
      for (int r = 0; r < 4; ++r){
        int m = m0 + mh * 64 + mf * 16 + lq * 4 + r;
        int nl = nq * 32 + nf * 16 + lr;
        if (m < M_ && nl < NHW)
          P[((size_t)ks * M_ + m) * N2_ + n0 + nl] =
            fmaf((float)accA[mf][nf][r], 0x1p-14f, (float)accB[mf][nf][r] * 0x1p-22f);
      }
}

// ---------------------------------------------------------------- K2b: reduce k-splits
__global__ __launch_bounds__(256) void k2b_reduce(const float* __restrict__ P,
                                                  float* __restrict__ G2){
  int j = blockIdx.x * 256 + threadIdx.x;
  if (j >= M_ * N2_) return;
  float s = 0.f;
  #pragma unroll
  for (int ks = 0; ks < KSPL; ++ks) s += P[(size_t)ks * (M_ * N2_) + j];
  G2[j] = s;
}

// ---------------------------------------------------------------- K3: LIF2+FC2+LIF3 scan
__global__ __launch_bounds__(256) void k3_scan(const float* __restrict__ G2,
                                               const float* __restrict__ w2,
                                               float* __restrict__ out){
  const int b = blockIdx.x;
  const int tid = threadIdx.x;
  const float w = (tid < N2_) ? w2[tid] : 0.f;
  float m2 = 0.f, m3 = 0.f;
  __shared__ float part[4];

  float nxt = (tid < N2_) ? G2[(size_t)b * N2_ + tid] : 0.f;
  for (int t = 0; t < T_; ++t){
    float g2v = nxt;
    if (t < T_ - 1 && tid < N2_) nxt = G2[(size_t)((t + 1) * B_ + b) * N2_ + tid];
    float nm = (m2 > 1.0f) ? 0.f : __fadd_rn(__fmul_rn(0.9f, m2), g2v);
    m2 = nm;
    float s = (m2 > 1.0f) ? w : 0.f;
    #pragma unroll
    for (int off = 32; off > 0; off >>= 1) s += __shfl_down(s, off, 64);
    if ((tid & 63) == 0) part[tid >> 6] = s;
    __syncthreads();
    if (tid == 0){
      float g3 = (part[0] + part[1]) + (part[2] + part[3]);
      m3 = __fadd_rn(__fmul_rn(0.95f, m3), g3);
      out[b * T_ + t] = m3;
    }
    __syncthreads();
  }
}

// ---------------------------------------------------------------- host
extern "C" void kernel_launch(void* const* d_in, const int* in_sizes, int n_in,
                              void* d_out, int out_size, void* d_ws, size_t ws_size,
                              hipStream_t stream){
  const float* x    = (const float*)d_in[0];
  const float* kern = (const float*)d_in[1];
  const float* w1   = (const float*)d_in[2];
  const float* w2   = (const float*)d_in[3];
  float* out = (float*)d_out;

  char* p = (char*)d_ws;
  unsigned char* z8 = (unsigned char*)p;     p += (size_t)M_ * K1N;            // 52.4 MB
  char* wa = p;                              p += (size_t)NP_ * K1N;           // 16.8 MB
  char* wb = p;                              p += (size_t)NP_ * K1N;           // 16.8 MB
  float* P  = (float*)p;                     p += (size_t)KSPL * M_ * N2_ * 4; // 20.5 MB
  float* G2 = (float*)p;                     p += (size_t)M_ * N2_ * 4;        // 0.64 MB

  size_t need = (size_t)(p - (char*)d_ws);
  if (ws_size < need) return;

  hipLaunchKernelGGL(k01_fused,  dim3(NCONV + NPERM), dim3(256), 0, stream,
                     x, kern, w1, z8, wa, wb);
  hipLaunchKernelGGL(k2_gemm,    dim3(448), dim3(512), 0, stream, z8, wa, wb, P);
  hipLaunchKernelGGL(k2b_reduce, dim3((M_ * N2_ + 255) / 256), dim3(256), 0, stream, P, G2);
  hipLaunchKernelGGL(k3_scan,    dim3(B_), dim3(256), 0, stream, G2, w2, out);
}

// Round 15
// 125.146 us; speedup vs baseline: 1.1378x; 1.0093x over previous
//
#include <hip/hip_runtime.h>
#include <hip/hip_bf16.h>

// Motion-detection Gauss-LIF SNN:
//   K01 (fused, heterogeneous 256-thread blocks) — r10-proven form:
//     blocks [0,512):    conv(16x9x9) via MFMA bf16 16x16x32 + LIF1 ->
//                        Z1 [800][65536] i8 {0,1} in k'-order (SW=84,
//                        narrow wave-parity reads, separate limb arrays).
//     blocks [512,6912): w1 -> i8 (A,B) split, k'-permuted, conflict-free LDS.
//   K2: Z1 @ w1^T via two mfma_i32_16x16x64_i8 (exact i32). BM=128, KSPL=32,
//       N split in 2 halves (100 cols, padded 128), grid 448, XCD-chunked.
//       NEW: FULL double-buffer (A and B) -> 1 barrier per k-step; next-tile
//       global loads issue post-barrier, LDS writes land post-MFMA.
//   K2b: reduce partials; K3: sequential LIF2+FC2+LIF3 scan.
// LIF recurrences __fmul_rn/__fadd_rn (no contract). Deterministic order.

typedef __attribute__((ext_vector_type(8))) short short8;
typedef __attribute__((ext_vector_type(4))) float f32x4;
typedef __attribute__((ext_vector_type(4))) int   i32x4;

#define B_   16
#define T_   50
#define HW_  4096
#define K1N  65536
#define M_   800
#define N2_  200
#define NP_  256
#define KSPL 32
#define BM2  128
#define BK2  64
#define KCH  (K1N / KSPL)  // 2048
#define MT2  7             // ceil(800/128)
#define NHW  100           // real n per half
#define SW   84            // conv tile stride (ushorts), r7/r10-proven
#define TILE (12 * SW)     // 1008
#define NCONV 512
#define NPERM (200 * 32)

static __device__ __forceinline__ short8 mk8(uint a, uint b, uint c, uint d){
  union { uint u[4]; short8 v; } x;
  x.u[0] = a; x.u[1] = b; x.u[2] = c; x.u[3] = d;
  return x.v;
}
static __device__ __forceinline__ uint fnl(uint a, uint b){ return (a >> 16) | (b << 16); }

// ---------------------------------------------------------------- conv helpers (r7/r10)
template<bool WODD>
static __device__ __forceinline__ void rd5(const uint* p, int dw, uint e[5]){
  if (WODD){
    e[0] = p[dw];
    uint2 a = *(const uint2*)(p + dw + 1);
    uint2 b = *(const uint2*)(p + dw + 3);
    e[1] = a.x; e[2] = a.y; e[3] = b.x; e[4] = b.y;
  } else {
    uint2 a = *(const uint2*)(p + dw);
    uint2 b = *(const uint2*)(p + dw + 2);
    e[0] = a.x; e[1] = a.y; e[2] = b.x; e[3] = b.y;
    e[4] = p[dw + 4];
  }
}

template<bool WODD>
static __device__ __forceinline__ void conv_phase(const uint* T0, const uint* T1,
                                                  int bdw,
                                                  const short8 (&afh)[5],
                                                  const short8 (&afl)[5],
                                                  f32x4& acc0, f32x4& acc1){
  #pragma unroll
  for (int ks = 0; ks < 5; ++ks){
    const int dw = bdw + (SW / 2) * 2 * ks;   // +84 dwords per kstep (2 rows)
    uint h[5], m[5];
    rd5<WODD>(T0, dw, h);
    rd5<WODD>(T1, dw, m);
    short8 bh0 = mk8(h[0], h[1], h[2], h[3]);
    short8 bm0 = mk8(m[0], m[1], m[2], m[3]);
    acc0 = __builtin_amdgcn_mfma_f32_16x16x32_bf16(afh[ks], bh0, acc0, 0, 0, 0);
    acc0 = __builtin_amdgcn_mfma_f32_16x16x32_bf16(afh[ks], bm0, acc0, 0, 0, 0);
    acc0 = __builtin_amdgcn_mfma_f32_16x16x32_bf16(afl[ks], bh0, acc0, 0, 0, 0);
    short8 bh1 = mk8(fnl(h[0], h[1]), fnl(h[1], h[2]), fnl(h[2], h[3]), fnl(h[3], h[4]));
    short8 bm1 = mk8(fnl(m[0], m[1]), fnl(m[1], m[2]), fnl(m[2], m[3]), fnl(m[3], m[4]));
    acc1 = __builtin_amdgcn_mfma_f32_16x16x32_bf16(afh[ks], bh1, acc1, 0, 0, 0);
    acc1 = __builtin_amdgcn_mfma_f32_16x16x32_bf16(afh[ks], bm1, acc1, 0, 0, 0);
    acc1 = __builtin_amdgcn_mfma_f32_16x16x32_bf16(afl[ks], bh1, acc1, 0, 0, 0);
  }
}

static __device__ __forceinline__ void stage_tile(ushort* Th, ushort* Tm,
                                                  int eb, float4 f){
  float vv[4] = {f.x, f.y, f.z, f.w};
  ushort sh[4], sm[4];
  #pragma unroll
  for (int ii = 0; ii < 4; ++ii){
    __hip_bfloat16 h = __float2bfloat16(vv[ii]);
    float t1 = vv[ii] - __bfloat162float(h);
    __hip_bfloat16 m = __float2bfloat16(t1);
    sh[ii] = *reinterpret_cast<ushort*>(&h);
    sm[ii] = *reinterpret_cast<ushort*>(&m);
  }
  *(ushort4*)(Th + eb) = make_ushort4(sh[0], sh[1], sh[2], sh[3]);
  *(ushort4*)(Tm + eb) = make_ushort4(sm[0], sm[1], sm[2], sm[3]);
}

// ---------------------------------------------------------------- K01 (r10 verbatim)
__global__ __launch_bounds__(256) void k01_fused(const float* __restrict__ x,
                                                 const float* __restrict__ kern,
                                                 const float* __restrict__ w1,
                                                 unsigned char* __restrict__ zout,
                                                 char* __restrict__ wa,
                                                 char* __restrict__ wb){
  __shared__ __align__(16) ushort smem[9152];
  const int bid = blockIdx.x;
  const int tid = threadIdx.x;

  if (bid >= NCONV){
    // ---------------- w1 -> i8 (A,B) split + k'-permute, conflict-free ------
    uint* la = (uint*)smem;               // 520 uints (o-padded)
    uint* lb = ((uint*)smem) + 528;
    const int bid2 = bid - NCONV;
    const int n = bid2 >> 5;
    const int strip = bid2 & 31;
    const int p128 = tid & 127;
    const int qp   = tid >> 7;            // 0 or 1
    const int o = p128 & 7, s = p128 >> 3;
    const float* src = w1 + (size_t)n * K1N + strip * 128 + p128;
    #pragma unroll
    for (int qi = 0; qi < 2; ++qi){
      const int q = 2 * qp + qi;
      uint ua = 0, ub = 0;
      #pragma unroll
      for (int r = 0; r < 4; ++r){
        float v = src[(size_t)(4 * q + r) * 4096];
        float af = rintf(v * 16384.f);     // |af| <= 64
        float rr = v - af * 0x1p-14f;      // exact (Sterbenz)
        float bf = rintf(rr * 0x1p22f);    // in [-128, 128]
        int A = (int)af, Bq = (int)bf;
        if (Bq == 128){ A += 1; Bq = -128; }
        ua |= ((uint)(A & 255))  << (8 * r);
        ub |= ((uint)(Bq & 255)) << (8 * r);
      }
      const int u = 64 * o + 4 * s + q + o;   // +o pad -> <=2-way (free)
      la[u] = ua;
      lb[u] = ub;
    }
    __syncthreads();
    {
      const int j0 = 2 * tid;               // 0..510
      const int o2 = j0 >> 6;
      uint a0 = la[j0 + o2], a1 = la[j0 + 1 + o2];
      uint b0 = lb[j0 + o2], b1 = lb[j0 + 1 + o2];
      const size_t ob = (size_t)n * K1N + strip * 2048 + (size_t)j0 * 4;
      *(uint2*)(wa + ob) = make_uint2(a0, a1);
      *(uint2*)(wb + ob) = make_uint2(b0, b1);
    }
    return;
  }

  // ---------------- conv + LIF1 path (r10 verbatim) ----------------
  ushort* Ah  = smem;
  ushort* Alo = smem + 2560;
  ushort* Tt  = smem + 5120;               // [buf][limb][TILE]

  const int strip = bid & 31;
  const int b = bid >> 5;
  const int w = tid >> 6;
  const int l = tid & 63;
  const int q = l >> 4;
  const int s = l & 15;

  for (int slot = tid; slot < 16 * 160; slot += 256){
    int ch = slot / 160, kk = slot - ch * 160;
    int dy = kk >> 4, dx = kk & 15;
    float v = 0.f;
    if (dy < 9 && dx < 9) v = kern[ch * 81 + dy * 9 + dx];
    __hip_bfloat16 h = __float2bfloat16(v);
    float hf = __bfloat162float(h);
    __hip_bfloat16 lo = __float2bfloat16(v - hf);
    Ah[slot]  = *reinterpret_cast<ushort*>(&h);
    Alo[slot] = *reinterpret_cast<ushort*>(&lo);
  }

  const bool sact = tid < 240;
  const int sr = tid / 20, sc4 = tid - sr * 20;
  const int r0 = 2 * strip - 4;
  const int imr = r0 + sr;
  const bool sin = sact && imr >= 0 && imr < 64 && sc4 >= 1 && sc4 <= 16;
  const float* xb = x + (size_t)b * (T_ * HW_);
  const float* xsrc = xb + (sin ? (imr * 64 + (sc4 - 1) * 4) : 0);
  const int eb = sr * SW + sc4 * 4;

  {
    float4 f0 = make_float4(0.f, 0.f, 0.f, 0.f);
    if (sin) f0 = *(const float4*)(xsrc);
    if (sact) stage_tile(Tt + 0 * TILE, Tt + 1 * TILE, eb, f0);
  }
  __syncthreads();

  short8 afh[5], afl[5];
  #pragma unroll
  for (int ks = 0; ks < 5; ++ks){
    afh[ks] = *(const short8*)(Ah + s * 160 + ks * 32 + q * 8);
    afl[ks] = *(const short8*)(Alo + s * 160 + ks * 32 + q * 8);
  }

  const int p0 = (s >> 3) + (q >> 1);
  const int bdw = 42 * p0 + 4 * (s & 7) + 4 * (q & 1) + w;
  const bool wodd = (w & 1) != 0;

  float m1v[2][4];
  #pragma unroll
  for (int oi = 0; oi < 2; ++oi)
    #pragma unroll
    for (int r = 0; r < 4; ++r) m1v[oi][r] = 0.f;

  for (int t = 0; t < T_; ++t){
    __syncthreads();                           // tile t&1 ready
    float4 nfx = make_float4(0.f, 0.f, 0.f, 0.f);
    if (t + 1 < T_ && sin) nfx = *(const float4*)(xsrc + (size_t)(t + 1) * HW_);

    const int bb = t & 1;
    const uint* T0 = (const uint*)(Tt + (bb * 2 + 0) * TILE);
    const uint* T1 = (const uint*)(Tt + (bb * 2 + 1) * TILE);
    f32x4 acc0 = (f32x4)(0.f), acc1 = (f32x4)(0.f);
    if (wodd) conv_phase<true >(T0, T1, bdw, afh, afl, acc0, acc1);
    else      conv_phase<false>(T0, T1, bdw, afh, afl, acc0, acc1);

    const size_t zr = ((size_t)(t * B_ + b)) * K1N + strip * 2048 + s * 16 + q * 4;
    {
      uint zw = 0;
      #pragma unroll
      for (int r = 0; r < 4; ++r){
        float m = m1v[0][r];
        float nm = (m > 1.0f) ? 0.0f : __fadd_rn(__fmul_rn(0.9f, m), acc0[r]);
        m1v[0][r] = nm;
        if (nm > 1.0f) zw |= (1u << (8 * r));
      }
      *(uint*)(zout + zr + (size_t)(2 * w) * 256) = zw;
    }
    {
      uint zw = 0;
      #pragma unroll
      for (int r = 0; r < 4; ++r){
        float m = m1v[1][r];
        float nm = (m > 1.0f) ? 0.0f : __fadd_rn(__fmul_rn(0.9f, m), acc1[r]);
        m1v[1][r] = nm;
        if (nm > 1.0f) zw |= (1u << (8 * r));
      }
      *(uint*)(zout + zr + (size_t)(2 * w + 1) * 256) = zw;
    }

    if (t + 1 < T_ && sact)
      stage_tile(Tt + ((bb ^ 1) * 2 + 0) * TILE, Tt + ((bb ^ 1) * 2 + 1) * TILE, eb, nfx);
  }
}

// ---------------------------------------------------------------- K2 prefetch loader (i8)
// A: 128 rows x 64 k (512 x uint4); B half: 256 rows (wa 0-127, wb 128-255)
static __device__ __forceinline__ void k2_load(const unsigned char* __restrict__ z,
                                               const char* __restrict__ wa,
                                               const char* __restrict__ wb,
                                               int m0, int n0, int kg, int tid,
                                               uint4& pa, uint4 pb[2]){
  {
    int row = tid >> 2, c16 = tid & 3;
    int m = m0 + row;
    pa = make_uint4(0, 0, 0, 0);
    if (m < M_) pa = *(const uint4*)(z + (size_t)m * K1N + kg + c16 * 16);
  }
  #pragma unroll
  for (int i = 0; i < 2; ++i){
    int idx = tid + 512 * i;               // 0..1023
    int g   = idx >> 2;                    // 0..255
    int c16 = idx & 3;
    int sel = g >> 7;
    int rh  = g & 127;
    const char* src = sel ? wb : wa;
    pb[i] = make_uint4(0, 0, 0, 0);
    if (rh < NHW) pb[i] = *(const uint4*)(src + (size_t)(n0 + rh) * K1N + kg + c16 * 16);
  }
}

// ---------------------------------------------------------------- K2: i8 MFMA GEMM
// grid 448 = 8 XCDs x (ks(4) x mt(7) x nh(2)); block 512 = 8 waves
// (2 m-halves x 4 n-quads of 32). FULL A+B double-buffer: 1 barrier/k-step;
// global prefetch issues post-barrier, LDS writes land post-MFMA.
__global__ __launch_bounds__(512) void k2_gemm(const unsigned char* __restrict__ z,
                                               const char* __restrict__ wa,
                                               const char* __restrict__ wb,
                                               float* __restrict__ P){
  __shared__ __align__(16) unsigned char Al[2][128 * 80];   // 2 x 10240 B
  __shared__ __align__(16) unsigned char Bw[2][256 * 80];   // 2 x 20480 B

  const int bid = blockIdx.x;
  const int L = (bid & 7) * 56 + (bid >> 3);      // bijective: 448 = 8*56
  const int ks = L / 14;                           // 0..31 (4 per XCD)
  const int rem = L % 14;
  const int mt = rem >> 1;
  const int nh = rem & 1;
  const int m0 = mt * BM2;
  const int n0 = nh * NHW;
  const int k0 = ks * KCH;
  const int tid = threadIdx.x;
  const int wv = tid >> 6;
  const int mh = wv >> 2;         // m-half (64 rows)
  const int nq = wv & 3;          // n-quad (32 cols)
  const int l  = tid & 63;
  const int lr = l & 15;
  const int lq = l >> 4;

  const i32x4 zero4 = {0, 0, 0, 0};
  i32x4 accA[4][2], accB[4][2];
  #pragma unroll
  for (int mf = 0; mf < 4; ++mf)
    #pragma unroll
    for (int nf = 0; nf < 2; ++nf){ accA[mf][nf] = zero4; accB[mf][nf] = zero4; }

  // prologue: tile 0 -> buf 0
  uint4 pa, pb[2];
  k2_load(z, wa, wb, m0, n0, k0, tid, pa, pb);
  {
    int row = tid >> 2, c16 = tid & 3;
    *(uint4*)(&Al[0][row * 80 + c16 * 16]) = pa;
  }
  #pragma unroll
  for (int i = 0; i < 2; ++i){
    int idx = tid + 512 * i;
    int g = idx >> 2, c16 = idx & 3;
    *(uint4*)(&Bw[0][g * 80 + c16 * 16]) = pb[i];
  }

  #pragma unroll 1
  for (int kc = 0; kc < KCH; kc += BK2){
    const int cur = (kc >> 6) & 1;
    __syncthreads();                            // buf[cur] published

    const bool more = (kc + BK2 < KCH);
    if (more) k2_load(z, wa, wb, m0, n0, k0 + kc + BK2, tid, pa, pb);

    i32x4 af[4], ba[2], bbf[2];
    #pragma unroll
    for (int mf = 0; mf < 4; ++mf)
      af[mf] = *(const i32x4*)(&Al[cur][(mh * 64 + mf * 16 + lr) * 80 + lq * 16]);
    #pragma unroll
    for (int nf = 0; nf < 2; ++nf){
      ba[nf]  = *(const i32x4*)(&Bw[cur][(nq * 32 + nf * 16 + lr) * 80 + lq * 16]);
      bbf[nf] = *(const i32x4*)(&Bw[cur][(128 + nq * 32 + nf * 16 + lr) * 80 + lq * 16]);
    }
    #pragma unroll
    for (int mf = 0; mf < 4; ++mf)
      #pragma unroll
      for (int nf = 0; nf < 2; ++nf){
        accA[mf][nf] = __builtin_amdgcn_mfma_i32_16x16x64_i8(af[mf], ba[nf],  accA[mf][nf], 0, 0, 0);
        accB[mf][nf] = __builtin_amdgcn_mfma_i32_16x16x64_i8(af[mf], bbf[nf], accB[mf][nf], 0, 0, 0);
      }

    if (more){
      {
        int row = tid >> 2, c16 = tid & 3;
        *(uint4*)(&Al[cur ^ 1][row * 80 + c16 * 16]) = pa;
      }
      #pragma unroll
      for (int i = 0; i < 2; ++i){
        int idx = tid + 512 * i;
        int g = idx >> 2, c16 = idx & 3;
        *(uint4*)(&Bw[cur ^ 1][g * 80 + c16 * 16]) = pb[i];
      }
    }
  }

  // epilogue: C row = lq*4+reg (m), col = lr (n); combine exact int sums
  #pragma unroll
  for (int mf = 0; mf < 4; ++mf)
    #pragma unroll
    for (int nf = 0; nf < 2; ++nf)
      #pragma unroll
      for (int r = 0; r < 4; ++r){
        int m = m0 + mh * 64 + mf * 16 + lq * 4 + r;
        int nl = nq * 32 + nf * 16 + lr;
        if (m < M_ && nl < NHW)
          P[((size_t)ks * M_ + m) * N2_ + n0 + nl] =
            fmaf((float)accA[mf][nf][r], 0x1p-14f, (float)accB[mf][nf][r] * 0x1p-22f);
      }
}

// ---------------------------------------------------------------- K2b: reduce k-splits
__global__ __launch_bounds__(256) void k2b_reduce(const float* __restrict__ P,
                                                  float* __restrict__ G2){
  int j = blockIdx.x * 256 + threadIdx.x;
  if (j >= M_ * N2_) return;
  float s = 0.f;
  #pragma unroll
  for (int ks = 0; ks < KSPL; ++ks) s += P[(size_t)ks * (M_ * N2_) + j];
  G2[j] = s;
}

// ---------------------------------------------------------------- K3: LIF2+FC2+LIF3 scan
__global__ __launch_bounds__(256) void k3_scan(const float* __restrict__ G2,
                                               const float* __restrict__ w2,
                                               float* __restrict__ out){
  const int b = blockIdx.x;
  const int tid = threadIdx.x;
  const float w = (tid < N2_) ? w2[tid] : 0.f;
  float m2 = 0.f, m3 = 0.f;
  __shared__ float part[4];

  float nxt = (tid < N2_) ? G2[(size_t)b * N2_ + tid] : 0.f;
  for (int t = 0; t < T_; ++t){
    float g2v = nxt;
    if (t < T_ - 1 && tid < N2_) nxt = G2[(size_t)((t + 1) * B_ + b) * N2_ + tid];
    float nm = (m2 > 1.0f) ? 0.f : __fadd_rn(__fmul_rn(0.9f, m2), g2v);
    m2 = nm;
    float s = (m2 > 1.0f) ? w : 0.f;
    #pragma unroll
    for (int off = 32; off > 0; off >>= 1) s += __shfl_down(s, off, 64);
    if ((tid & 63) == 0) part[tid >> 6] = s;
    __syncthreads();
    if (tid == 0){
      float g3 = (part[0] + part[1]) + (part[2] + part[3]);
      m3 = __fadd_rn(__fmul_rn(0.95f, m3), g3);
      out[b * T_ + t] = m3;
    }
    __syncthreads();
  }
}

// ---------------------------------------------------------------- host
extern "C" void kernel_launch(void* const* d_in, const int* in_sizes, int n_in,
                              void* d_out, int out_size, void* d_ws, size_t ws_size,
                              hipStream_t stream){
  const float* x    = (const float*)d_in[0];
  const float* kern = (const float*)d_in[1];
  const float* w1   = (const float*)d_in[2];
  const float* w2   = (const float*)d_in[3];
  float* out = (float*)d_out;

  char* p = (char*)d_ws;
  unsigned char* z8 = (unsigned char*)p;     p += (size_t)M_ * K1N;            // 52.4 MB
  char* wa = p;                              p += (size_t)NP_ * K1N;           // 16.8 MB
  char* wb = p;                              p += (size_t)NP_ * K1N;           // 16.8 MB
  float* P  = (float*)p;                     p += (size_t)KSPL * M_ * N2_ * 4; // 20.5 MB
  float* G2 = (float*)p;                     p += (size_t)M_ * N2_ * 4;        // 0.64 MB

  size_t need = (size_t)(p - (char*)d_ws);
  if (ws_size < need) return;

  hipLaunchKernelGGL(k01_fused,  dim3(NCONV + NPERM), dim3(256), 0, stream,
                     x, kern, w1, z8, wa, wb);
  hipLaunchKernelGGL(k2_gemm,    dim3(448), dim3(512), 0, stream, z8, wa, wb, P);
  hipLaunchKernelGGL(k2b_reduce, dim3((M_ * N2_ + 255) / 256), dim3(256), 0, stream, P, G2);
  hipLaunchKernelGGL(k3_scan,    dim3(B_), dim3(256), 0, stream, G2, w2, out);
}